// Round 19
// baseline (123.066 us; speedup 1.0000x reference)
//
#include <hip/hip_runtime.h>
#include <hip/hip_bf16.h>

typedef __attribute__((ext_vector_type(8))) short short8;
typedef __attribute__((ext_vector_type(4))) float f32x4;
typedef unsigned int u32;

#define LDSW 136  // padded w1 row stride (bf16) = 272 B

// round-to-nearest-even f32 -> bf16
static __device__ __forceinline__ ushort f2bf(float f) {
  unsigned int u = __builtin_bit_cast(unsigned int, f);
  u += 0x7fffu + ((u >> 16) & 1u);
  return (ushort)(u >> 16);
}

// ---------------- kernel 1: FUSED lin + colsum from ONE gload_lds staging ------------------
// R18 decomposition: colsum 31us (at the 3.3 TB/s gload_lds read ceiling) + gemm 30us — x
// streamed twice. Both kernels consume the SAME 64x128 tile, so fuse: one cold pass over x
// (gload_lds, the proven-fast path — R8/R9's fused failures used the 1.7 TB/s VGPR path),
// computing colsum partial AND lin = x@w1 (stored WITHOUT t; add_t pass finishes it against
// L3-dirty out at the measured ~12 TB/s RMW rate). w1 is packed per-block directly from f32
// (64KB, L2-broadcast, hidden under the ~2.5us/block gload_lds wait).
__global__ __launch_bounds__(256) void fused_lin_cs_kernel(const float* __restrict__ x,
                                                           const float* __restrict__ w1,
                                                           float* __restrict__ out,
                                                           float4* __restrict__ partial4) {
  __shared__ ushort w1t[128 * LDSW];  // 34816 B
  __shared__ float xt[8192];          // 32768 B: 64 rows x 128 cols
  __shared__ float4 red[8][32];       // 4096 B  (total 71680 B -> 2 blocks/CU)
  int tid = threadIdx.x;
  int lane = tid & 63;
  int wave = tid >> 6;

  // issue x-tile staging FIRST (async; w1 packing hides under it)
  {
    const float* gbase = x + (size_t)blockIdx.x * 8192 + (size_t)(wave * 8) * 256 + lane * 4;
    float* lbase = xt + (wave * 8) * 256;  // wave-uniform
#pragma unroll
    for (int i = 0; i < 8; ++i) {
      __builtin_amdgcn_global_load_lds(
          (const __attribute__((address_space(1))) u32*)(gbase + i * 256),
          (__attribute__((address_space(3))) u32*)(lbase + i * 256), 16, 0, 0);
    }
  }

  // pack w1 f32 -> bf16 [col][k] into LDS (reads L2-broadcast; scattered b16 LDS writes)
  {
#pragma unroll
    for (int i = 0; i < 16; ++i) {
      int idx = tid + i * 256;          // 4096 float4 = 16384 elems
      int k = idx >> 5;                 // row of w1
      int c4 = idx & 31;                // float4 col group
      float4 v = *reinterpret_cast<const float4*>(w1 + k * 128 + c4 * 4);
      w1t[(c4 * 4 + 0) * LDSW + k] = f2bf(v.x);
      w1t[(c4 * 4 + 1) * LDSW + k] = f2bf(v.y);
      w1t[(c4 * 4 + 2) * LDSW + k] = f2bf(v.z);
      w1t[(c4 * 4 + 3) * LDSW + k] = f2bf(v.w);
    }
  }
  __syncthreads();  // drains gload_lds (vmcnt) + w1t writes

  // ---- colsum consume (R10-verified mapping) ----
  {
    int c4 = tid & 31;
    int rg = tid >> 5;
    const float4* tile4 = reinterpret_cast<const float4*>(xt);
    float4 acc = {0.f, 0.f, 0.f, 0.f};
#pragma unroll
    for (int k = 0; k < 8; ++k) {
      float4 v = tile4[(rg + 8 * k) * 32 + c4];
      acc.x += v.x; acc.y += v.y; acc.z += v.z; acc.w += v.w;
    }
    red[rg][c4] = acc;
  }
  __syncthreads();
  if (tid < 32) {
    float4 s = red[0][tid];
#pragma unroll
    for (int g = 1; g < 8; ++g) {
      float4 v = red[g][tid];
      s.x += v.x; s.y += v.y; s.z += v.z; s.w += v.w;
    }
    partial4[(size_t)blockIdx.x * 32 + tid] = s;
  }

  // ---- GEMM consume (R18-verified): lin = x @ w1, stored WITHOUT t ----
  int c = lane & 15;    // A row-in-tile / B col / D col
  int kg = lane >> 4;   // k-group 0..3
  int row = wave * 16 + c;
  int rbase = blockIdx.x * 64 + wave * 16;

  f32x4 acc[8];
#pragma unroll
  for (int nb = 0; nb < 8; ++nb) acc[nb] = (f32x4){0.f, 0.f, 0.f, 0.f};

#pragma unroll
  for (int kb = 0; kb < 4; ++kb) {
    int k0 = kb * 32 + kg * 8;
    float4 a0 = *reinterpret_cast<const float4*>(&xt[row * 128 + k0]);
    float4 a1 = *reinterpret_cast<const float4*>(&xt[row * 128 + k0 + 4]);
    short8 afrag;
    afrag[0] = (short)f2bf(a0.x);
    afrag[1] = (short)f2bf(a0.y);
    afrag[2] = (short)f2bf(a0.z);
    afrag[3] = (short)f2bf(a0.w);
    afrag[4] = (short)f2bf(a1.x);
    afrag[5] = (short)f2bf(a1.y);
    afrag[6] = (short)f2bf(a1.z);
    afrag[7] = (short)f2bf(a1.w);
#pragma unroll
    for (int nb = 0; nb < 8; ++nb) {
      short8 bfrag = *reinterpret_cast<const short8*>(&w1t[(nb * 16 + c) * LDSW + k0]);
      acc[nb] = __builtin_amdgcn_mfma_f32_16x16x32_bf16(afrag, bfrag, acc[nb], 0, 0, 0);
    }
  }

  // D layout (m89-verified): col = lane&15, row = (lane>>4)*4 + reg
#pragma unroll
  for (int nb = 0; nb < 8; ++nb) {
    int col = nb * 16 + c;
#pragma unroll
    for (int i = 0; i < 4; ++i) {
      out[(size_t)(rbase + kg * 4 + i) * 128 + col] = acc[nb][i];
    }
  }
}

// ---------------- kernel 2: reduce partial[3125][128] -> partial2[128][128] ----------------
__global__ __launch_bounds__(256) void reduce_kernel(const float* __restrict__ partial,
                                                     float* __restrict__ partial2,
                                                     int nb) {
  int tid = threadIdx.x;
  int j = tid & 127;
  int orow = blockIdx.x * 2 + (tid >> 7);
  float s = 0.f;
  for (int r = orow; r < nb; r += 128) s += partial[(size_t)r * 128 + j];
  partial2[orow * 128 + j] = s;
}

// ---------------- kernel 3: t = (pooled @ w2)/n + bias  (1 block x 1024 thr) ---------------
__global__ __launch_bounds__(1024) void transmit_kernel(const float* __restrict__ partial,
                                                        const float* __restrict__ w2,
                                                        const float* __restrict__ bias,
                                                        float* __restrict__ t, int n,
                                                        int nblocks) {
  __shared__ float red[8][128];
  __shared__ float pooled[128];
  int tid = threadIdx.x;
  int j = tid & 127;
  int g = tid >> 7;

  float s = 0.f;
  for (int b = g; b < nblocks; b += 8) s += partial[b * 128 + j];
  red[g][j] = s;
  __syncthreads();
  if (tid < 128) {
    float p = 0.f;
#pragma unroll
    for (int gg = 0; gg < 8; ++gg) p += red[gg][j];
    pooled[j] = p;
  }
  __syncthreads();

  float acc = 0.f;
#pragma unroll
  for (int ii = 0; ii < 16; ++ii) {
    int i = g * 16 + ii;
    acc += pooled[i] * w2[i * 128 + j];
  }
  __syncthreads();
  red[g][j] = acc;
  __syncthreads();
  if (tid < 128) {
    float a = 0.f;
#pragma unroll
    for (int gg = 0; gg < 8; ++gg) a += red[gg][j];
    t[j] = a / (float)n + bias[j];
  }
}

// ---------------- kernel 4: out += t  (R9-verified; L3-dirty RMW at ~12 TB/s) --------------
// 3125 blocks x 256 thr x 8 float4 = 6,400,000 exact. 800000 % 32 == 0 -> constant t-phase.
__global__ __launch_bounds__(256) void add_t_kernel(float4* __restrict__ out4,
                                                    const float4* __restrict__ t4) {
  int idx = blockIdx.x * 256 + threadIdx.x;  // 0..799999
  float4 tv = t4[idx & 31];
#pragma unroll
  for (int b = 0; b < 2; ++b) {
    float4 v0 = out4[(size_t)idx + (size_t)(b * 4 + 0) * 800000u];
    float4 v1 = out4[(size_t)idx + (size_t)(b * 4 + 1) * 800000u];
    float4 v2 = out4[(size_t)idx + (size_t)(b * 4 + 2) * 800000u];
    float4 v3 = out4[(size_t)idx + (size_t)(b * 4 + 3) * 800000u];
    v0.x += tv.x; v0.y += tv.y; v0.z += tv.z; v0.w += tv.w;
    v1.x += tv.x; v1.y += tv.y; v1.z += tv.z; v1.w += tv.w;
    v2.x += tv.x; v2.y += tv.y; v2.z += tv.z; v2.w += tv.w;
    v3.x += tv.x; v3.y += tv.y; v3.z += tv.z; v3.w += tv.w;
    out4[(size_t)idx + (size_t)(b * 4 + 0) * 800000u] = v0;
    out4[(size_t)idx + (size_t)(b * 4 + 1) * 800000u] = v1;
    out4[(size_t)idx + (size_t)(b * 4 + 2) * 800000u] = v2;
    out4[(size_t)idx + (size_t)(b * 4 + 3) * 800000u] = v3;
  }
}

extern "C" void kernel_launch(void* const* d_in, const int* in_sizes, int n_in,
                              void* d_out, int out_size, void* d_ws, size_t ws_size,
                              hipStream_t stream) {
  const float* x = (const float*)d_in[0];
  const float* w1 = (const float*)d_in[1];
  const float* w2 = (const float*)d_in[2];
  const float* bias = (const float*)d_in[3];
  float* out = (float*)d_out;
  int n = in_sizes[0] / 128;  // 200000
  int nb = n / 64;            // 3125

  char* ws = (char*)d_ws;
  float* t = (float*)ws;                     // 512 B
  float* partial = (float*)(ws + 35328);     // 3125*128*4 = 1,600,000 B -> ends 1,635,328
  float* partial2 = (float*)(ws + 1635328);  // 65,536 B

  hipLaunchKernelGGL(fused_lin_cs_kernel, dim3(nb), dim3(256), 0, stream,
                     x, w1, out, (float4*)partial);
  hipLaunchKernelGGL(reduce_kernel, dim3(64), dim3(256), 0, stream, partial, partial2, nb);
  hipLaunchKernelGGL(transmit_kernel, dim3(1), dim3(1024), 0, stream,
                     partial2, w2, bias, t, n, 128);
  hipLaunchKernelGGL(add_t_kernel, dim3(nb), dim3(256), 0, stream,
                     (float4*)out, (const float4*)t);
}

// Round 20
// 104.128 us; speedup vs baseline: 1.1819x; 1.1819x over previous
//
#include <hip/hip_runtime.h>
#include <hip/hip_bf16.h>

typedef __attribute__((ext_vector_type(8))) short short8;
typedef __attribute__((ext_vector_type(4))) float f32x4;
typedef unsigned int u32;

#define LDSW 136  // padded w1 row stride (bf16) = 272 B

// round-to-nearest-even f32 -> bf16
static __device__ __forceinline__ ushort f2bf(float f) {
  unsigned int u = __builtin_bit_cast(unsigned int, f);
  u += 0x7fffu + ((u >> 16) & 1u);
  return (ushort)(u >> 16);
}

// ---------------- kernel 1: pack w1 (f32 row-major) -> bf16 [col][k] padded (ONCE) ---------
__global__ __launch_bounds__(256) void pack_w1_kernel(const float* __restrict__ w1,
                                                      ushort* __restrict__ w1p) {
  int tid = blockIdx.x * 256 + threadIdx.x;
  int k = tid >> 7;
  int c = tid & 127;
  w1p[c * LDSW + k] = f2bf(w1[k * 128 + c]);
}

// ---------------- kernel 2: FUSED lin + colsum from ONE gload_lds staging ------------------
// R19 lesson (counters): per-block w1 PACK into LDS was 16-way-conflicted scattered writes
// (SQ_LDS_BANK_CONFLICT 2.84e7 ~= 52us/CU — the entire 60us excess). v2 stages PRE-PACKED
// w1p with the R18-proven linear ulonglong2 copy (conflict-free). Everything else unchanged:
// one cold x pass (gload_lds, 3.3 TB/s path) feeding BOTH colsum and lin=x@w1; lin stored
// without t; add_t finishes against L3-dirty out.
__global__ __launch_bounds__(256) void fused_lin_cs_kernel(const float* __restrict__ x,
                                                           const ushort* __restrict__ w1p,
                                                           float* __restrict__ out,
                                                           float4* __restrict__ partial4) {
  __shared__ ushort w1t[128 * LDSW];  // 34816 B
  __shared__ float xt[8192];          // 32768 B: 64 rows x 128 cols
  __shared__ float4 red[8][32];       // 4096 B  (total 71680 B -> 2 blocks/CU)
  int tid = threadIdx.x;
  int lane = tid & 63;
  int wave = tid >> 6;

  // issue x-tile staging FIRST (async; w1t copy hides under it)
  {
    const float* gbase = x + (size_t)blockIdx.x * 8192 + (size_t)(wave * 8) * 256 + lane * 4;
    float* lbase = xt + (wave * 8) * 256;  // wave-uniform
#pragma unroll
    for (int i = 0; i < 8; ++i) {
      __builtin_amdgcn_global_load_lds(
          (const __attribute__((address_space(1))) u32*)(gbase + i * 256),
          (__attribute__((address_space(3))) u32*)(lbase + i * 256), 16, 0, 0);
    }
  }

  // stage pre-packed w1p -> LDS: 2176 x 16B linear chunks, conflict-free (R18-proven)
  {
    const ulonglong2* src = reinterpret_cast<const ulonglong2*>(w1p);
    ulonglong2* dst = reinterpret_cast<ulonglong2*>(w1t);
#pragma unroll
    for (int i = 0; i < 9; ++i) {
      int idx = tid + i * 256;
      if (idx < 2176) dst[idx] = src[idx];
    }
  }
  __syncthreads();  // drains gload_lds (vmcnt) + w1t writes (lgkmcnt)

  // ---- colsum consume (R10-verified mapping) ----
  {
    int c4 = tid & 31;
    int rg = tid >> 5;
    const float4* tile4 = reinterpret_cast<const float4*>(xt);
    float4 acc = {0.f, 0.f, 0.f, 0.f};
#pragma unroll
    for (int k = 0; k < 8; ++k) {
      float4 v = tile4[(rg + 8 * k) * 32 + c4];
      acc.x += v.x; acc.y += v.y; acc.z += v.z; acc.w += v.w;
    }
    red[rg][c4] = acc;
  }
  __syncthreads();
  if (tid < 32) {
    float4 s = red[0][tid];
#pragma unroll
    for (int g = 1; g < 8; ++g) {
      float4 v = red[g][tid];
      s.x += v.x; s.y += v.y; s.z += v.z; s.w += v.w;
    }
    partial4[(size_t)blockIdx.x * 32 + tid] = s;
  }

  // ---- GEMM consume (R18-verified): lin = x @ w1, stored WITHOUT t ----
  int c = lane & 15;    // A row-in-tile / B col / D col
  int kg = lane >> 4;   // k-group 0..3
  int row = wave * 16 + c;
  int rbase = blockIdx.x * 64 + wave * 16;

  f32x4 acc[8];
#pragma unroll
  for (int nb = 0; nb < 8; ++nb) acc[nb] = (f32x4){0.f, 0.f, 0.f, 0.f};

#pragma unroll
  for (int kb = 0; kb < 4; ++kb) {
    int k0 = kb * 32 + kg * 8;
    float4 a0 = *reinterpret_cast<const float4*>(&xt[row * 128 + k0]);
    float4 a1 = *reinterpret_cast<const float4*>(&xt[row * 128 + k0 + 4]);
    short8 afrag;
    afrag[0] = (short)f2bf(a0.x);
    afrag[1] = (short)f2bf(a0.y);
    afrag[2] = (short)f2bf(a0.z);
    afrag[3] = (short)f2bf(a0.w);
    afrag[4] = (short)f2bf(a1.x);
    afrag[5] = (short)f2bf(a1.y);
    afrag[6] = (short)f2bf(a1.z);
    afrag[7] = (short)f2bf(a1.w);
#pragma unroll
    for (int nb = 0; nb < 8; ++nb) {
      short8 bfrag = *reinterpret_cast<const short8*>(&w1t[(nb * 16 + c) * LDSW + k0]);
      acc[nb] = __builtin_amdgcn_mfma_f32_16x16x32_bf16(afrag, bfrag, acc[nb], 0, 0, 0);
    }
  }

  // D layout (m89-verified): col = lane&15, row = (lane>>4)*4 + reg
#pragma unroll
  for (int nb = 0; nb < 8; ++nb) {
    int col = nb * 16 + c;
#pragma unroll
    for (int i = 0; i < 4; ++i) {
      out[(size_t)(rbase + kg * 4 + i) * 128 + col] = acc[nb][i];
    }
  }
}

// ---------------- kernel 3: reduce partial[3125][128] -> partial2[128][128] ----------------
__global__ __launch_bounds__(256) void reduce_kernel(const float* __restrict__ partial,
                                                     float* __restrict__ partial2,
                                                     int nb) {
  int tid = threadIdx.x;
  int j = tid & 127;
  int orow = blockIdx.x * 2 + (tid >> 7);
  float s = 0.f;
  for (int r = orow; r < nb; r += 128) s += partial[(size_t)r * 128 + j];
  partial2[orow * 128 + j] = s;
}

// ---------------- kernel 4: t = (pooled @ w2)/n + bias  (1 block x 1024 thr) ---------------
__global__ __launch_bounds__(1024) void transmit_kernel(const float* __restrict__ partial,
                                                        const float* __restrict__ w2,
                                                        const float* __restrict__ bias,
                                                        float* __restrict__ t, int n,
                                                        int nblocks) {
  __shared__ float red[8][128];
  __shared__ float pooled[128];
  int tid = threadIdx.x;
  int j = tid & 127;
  int g = tid >> 7;

  float s = 0.f;
  for (int b = g; b < nblocks; b += 8) s += partial[b * 128 + j];
  red[g][j] = s;
  __syncthreads();
  if (tid < 128) {
    float p = 0.f;
#pragma unroll
    for (int gg = 0; gg < 8; ++gg) p += red[gg][j];
    pooled[j] = p;
  }
  __syncthreads();

  float acc = 0.f;
#pragma unroll
  for (int ii = 0; ii < 16; ++ii) {
    int i = g * 16 + ii;
    acc += pooled[i] * w2[i * 128 + j];
  }
  __syncthreads();
  red[g][j] = acc;
  __syncthreads();
  if (tid < 128) {
    float a = 0.f;
#pragma unroll
    for (int gg = 0; gg < 8; ++gg) a += red[gg][j];
    t[j] = a / (float)n + bias[j];
  }
}

// ---------------- kernel 5: out += t  (L3-dirty RMW) ---------------------------------------
// 3125 blocks x 256 thr x 8 float4 = 6,400,000 exact. 800000 % 32 == 0 -> constant t-phase.
__global__ __launch_bounds__(256) void add_t_kernel(float4* __restrict__ out4,
                                                    const float4* __restrict__ t4) {
  int idx = blockIdx.x * 256 + threadIdx.x;  // 0..799999
  float4 tv = t4[idx & 31];
#pragma unroll
  for (int b = 0; b < 2; ++b) {
    float4 v0 = out4[(size_t)idx + (size_t)(b * 4 + 0) * 800000u];
    float4 v1 = out4[(size_t)idx + (size_t)(b * 4 + 1) * 800000u];
    float4 v2 = out4[(size_t)idx + (size_t)(b * 4 + 2) * 800000u];
    float4 v3 = out4[(size_t)idx + (size_t)(b * 4 + 3) * 800000u];
    v0.x += tv.x; v0.y += tv.y; v0.z += tv.z; v0.w += tv.w;
    v1.x += tv.x; v1.y += tv.y; v1.z += tv.z; v1.w += tv.w;
    v2.x += tv.x; v2.y += tv.y; v2.z += tv.z; v2.w += tv.w;
    v3.x += tv.x; v3.y += tv.y; v3.z += tv.z; v3.w += tv.w;
    out4[(size_t)idx + (size_t)(b * 4 + 0) * 800000u] = v0;
    out4[(size_t)idx + (size_t)(b * 4 + 1) * 800000u] = v1;
    out4[(size_t)idx + (size_t)(b * 4 + 2) * 800000u] = v2;
    out4[(size_t)idx + (size_t)(b * 4 + 3) * 800000u] = v3;
  }
}

extern "C" void kernel_launch(void* const* d_in, const int* in_sizes, int n_in,
                              void* d_out, int out_size, void* d_ws, size_t ws_size,
                              hipStream_t stream) {
  const float* x = (const float*)d_in[0];
  const float* w1 = (const float*)d_in[1];
  const float* w2 = (const float*)d_in[2];
  const float* bias = (const float*)d_in[3];
  float* out = (float*)d_out;
  int n = in_sizes[0] / 128;  // 200000
  int nb = n / 64;            // 3125

  char* ws = (char*)d_ws;
  float* t = (float*)ws;                     // 512 B
  ushort* w1p = (ushort*)(ws + 512);         // 34,816 B -> ends 35,328
  float* partial = (float*)(ws + 35328);     // 3125*128*4 = 1,600,000 B -> ends 1,635,328
  float* partial2 = (float*)(ws + 1635328);  // 65,536 B

  hipLaunchKernelGGL(pack_w1_kernel, dim3(64), dim3(256), 0, stream, w1, w1p);
  hipLaunchKernelGGL(fused_lin_cs_kernel, dim3(nb), dim3(256), 0, stream,
                     x, w1p, out, (float4*)partial);
  hipLaunchKernelGGL(reduce_kernel, dim3(64), dim3(256), 0, stream, partial, partial2, nb);
  hipLaunchKernelGGL(transmit_kernel, dim3(1), dim3(1024), 0, stream,
                     partial2, w2, bias, t, n, 128);
  hipLaunchKernelGGL(add_t_kernel, dim3(nb), dim3(256), 0, stream,
                     (float4*)out, (const float4*)t);
}

// Round 21
// 72.061 us; speedup vs baseline: 1.7078x; 1.4450x over previous
//
#include <hip/hip_runtime.h>
#include <hip/hip_bf16.h>

typedef __attribute__((ext_vector_type(8))) short short8;
typedef __attribute__((ext_vector_type(4))) float f32x4;
typedef unsigned int u32;

#define LDSW 136       // padded w1 row stride (bf16) = 272 B
#define CS_BLOCKS 3125 // 64-row tiles
#define PK_BLOCKS 64   // pack_w1 folded into the colsum grid

// round-to-nearest-even f32 -> bf16
static __device__ __forceinline__ ushort f2bf(float f) {
  unsigned int u = __builtin_bit_cast(unsigned int, f);
  u += 0x7fffu + ((u >> 16) & 1u);
  return (ushort)(u >> 16);
}

// ---------------- kernel 1: colsum via global_load_lds  (+ pack_w1 folded in) --------------
// At the measured 3.3 TB/s cold-read ceiling (10 structures probed, R2-R20).
__global__ __launch_bounds__(256) void colsum_pack_kernel(const float* __restrict__ x,
                                                          const float* __restrict__ w1,
                                                          ushort* __restrict__ w1p,
                                                          float4* __restrict__ partial4) {
  __shared__ float tile[8192];     // 32 KB: 64 rows x 128 cols
  __shared__ float4 red[8][32];    // 4 KB  (36 KB -> 4 blocks/CU: stage latency hidden)
  int tid = threadIdx.x;

  if (blockIdx.x >= CS_BLOCKS) {  // pack path: 64 blocks x 256 = 16384 = 128*128
    int idx = (blockIdx.x - CS_BLOCKS) * 256 + tid;
    int k = idx >> 7, c = idx & 127;
    w1p[c * LDSW + k] = f2bf(w1[k * 128 + c]);
    return;
  }

  int lane = tid & 63;
  int wave = tid >> 6;
  const float* gbase = x + (size_t)blockIdx.x * 8192 + (size_t)(wave * 8) * 256 + lane * 4;
  float* lbase = tile + (wave * 8) * 256;  // wave-uniform
#pragma unroll
  for (int i = 0; i < 8; ++i) {
    __builtin_amdgcn_global_load_lds(
        (const __attribute__((address_space(1))) u32*)(gbase + i * 256),
        (__attribute__((address_space(3))) u32*)(lbase + i * 256), 16, 0, 0);
  }
  __syncthreads();  // vmcnt drain: tile complete

  int c4 = tid & 31;
  int rg = tid >> 5;
  const float4* tile4 = reinterpret_cast<const float4*>(tile);
  float4 acc = {0.f, 0.f, 0.f, 0.f};
#pragma unroll
  for (int k = 0; k < 8; ++k) {
    float4 v = tile4[(rg + 8 * k) * 32 + c4];
    acc.x += v.x; acc.y += v.y; acc.z += v.z; acc.w += v.w;
  }
  red[rg][c4] = acc;
  __syncthreads();
  if (tid < 32) {
    float4 s = red[0][tid];
#pragma unroll
    for (int g = 1; g < 8; ++g) {
      float4 v = red[g][tid];
      s.x += v.x; s.y += v.y; s.z += v.z; s.w += v.w;
    }
    partial4[(size_t)blockIdx.x * 32 + tid] = s;
  }
}

// ---------------- kernel 2: reduce partial[3125][128] -> partial2[128][128] ----------------
__global__ __launch_bounds__(256) void reduce_kernel(const float* __restrict__ partial,
                                                     float* __restrict__ partial2,
                                                     int nb) {
  int tid = threadIdx.x;
  int j = tid & 127;
  int orow = blockIdx.x * 2 + (tid >> 7);
  float s = 0.f;
  for (int r = orow; r < nb; r += 128) s += partial[(size_t)r * 128 + j];
  partial2[orow * 128 + j] = s;
}

// ---------------- kernel 3: t = (pooled @ w2)/n + bias  (1 block x 1024 thr) ---------------
__global__ __launch_bounds__(1024) void transmit_kernel(const float* __restrict__ partial,
                                                        const float* __restrict__ w2,
                                                        const float* __restrict__ bias,
                                                        float* __restrict__ t, int n,
                                                        int nblocks) {
  __shared__ float red[8][128];
  __shared__ float pooled[128];
  int tid = threadIdx.x;
  int j = tid & 127;
  int g = tid >> 7;

  float s = 0.f;
  for (int b = g; b < nblocks; b += 8) s += partial[b * 128 + j];
  red[g][j] = s;
  __syncthreads();
  if (tid < 128) {
    float p = 0.f;
#pragma unroll
    for (int gg = 0; gg < 8; ++gg) p += red[gg][j];
    pooled[j] = p;
  }
  __syncthreads();

  float acc = 0.f;
#pragma unroll
  for (int ii = 0; ii < 16; ++ii) {
    int i = g * 16 + ii;
    acc += pooled[i] * w2[i * 128 + j];
  }
  __syncthreads();
  red[g][j] = acc;
  __syncthreads();
  if (tid < 128) {
    float a = 0.f;
#pragma unroll
    for (int gg = 0; gg < 8; ++gg) a += red[gg][j];
    t[j] = a / (float)n + bias[j];
  }
}

// ---------------- kernel 4: out = x @ w1 + t, REVERSE tile order ---------------------------
// R21's single variable: block b consumes tile nb-1-b. After colsum, x's TAIL tiles are
// freshest in L3 (its own later tiles evicted the head); reading tail-first harvests those
// hits before out's dirty writes evict them, and the head tiles it reaches last were already
// cold (HBM either way). Predicted: FETCH 50 -> 30-40 MB.
__global__ __launch_bounds__(256) void gemm_lds_kernel(const float* __restrict__ x,
                                                       const ushort* __restrict__ w1p,
                                                       const float* __restrict__ tvec,
                                                       float* __restrict__ out) {
  __shared__ ushort w1t[128 * LDSW];  // 34816 B
  __shared__ float xt[8192];          // 32768 B
  __shared__ float t_lds[128];
  int tid = threadIdx.x;
  int lane = tid & 63;
  int wave = tid >> 6;
  int tb = (int)gridDim.x - 1 - (int)blockIdx.x;  // reverse tile mapping

  // stage packed w1 (L2-hot) via linear conflict-free copies
  {
    const ulonglong2* src = reinterpret_cast<const ulonglong2*>(w1p);
    ulonglong2* dst = reinterpret_cast<ulonglong2*>(w1t);
#pragma unroll
    for (int i = 0; i < 9; ++i) {
      int idx = tid + i * 256;
      if (idx < 2176) dst[idx] = src[idx];
    }
  }
  if (tid < 128) t_lds[tid] = tvec[tid];

  // stage x-tile via gload_lds (fast read path)
  {
    const float* gbase = x + (size_t)tb * 8192 + (size_t)(wave * 8) * 256 + lane * 4;
    float* lbase = xt + (wave * 8) * 256;  // wave-uniform
#pragma unroll
    for (int i = 0; i < 8; ++i) {
      __builtin_amdgcn_global_load_lds(
          (const __attribute__((address_space(1))) u32*)(gbase + i * 256),
          (__attribute__((address_space(3))) u32*)(lbase + i * 256), 16, 0, 0);
    }
  }
  __syncthreads();  // drains w1t copies + gload_lds

  int c = lane & 15;    // A row-in-tile / B col / D col
  int kg = lane >> 4;   // k-group 0..3
  int row = wave * 16 + c;
  int rbase = tb * 64 + wave * 16;

  f32x4 acc[8];
#pragma unroll
  for (int nb = 0; nb < 8; ++nb) acc[nb] = (f32x4){0.f, 0.f, 0.f, 0.f};

#pragma unroll
  for (int kb = 0; kb < 4; ++kb) {
    int k0 = kb * 32 + kg * 8;
    float4 a0 = *reinterpret_cast<const float4*>(&xt[row * 128 + k0]);
    float4 a1 = *reinterpret_cast<const float4*>(&xt[row * 128 + k0 + 4]);
    short8 afrag;
    afrag[0] = (short)f2bf(a0.x);
    afrag[1] = (short)f2bf(a0.y);
    afrag[2] = (short)f2bf(a0.z);
    afrag[3] = (short)f2bf(a0.w);
    afrag[4] = (short)f2bf(a1.x);
    afrag[5] = (short)f2bf(a1.y);
    afrag[6] = (short)f2bf(a1.z);
    afrag[7] = (short)f2bf(a1.w);
#pragma unroll
    for (int nb = 0; nb < 8; ++nb) {
      short8 bfrag = *reinterpret_cast<const short8*>(&w1t[(nb * 16 + c) * LDSW + k0]);
      acc[nb] = __builtin_amdgcn_mfma_f32_16x16x32_bf16(afrag, bfrag, acc[nb], 0, 0, 0);
    }
  }

  // D layout (m89-verified): col = lane&15, row = (lane>>4)*4 + reg
#pragma unroll
  for (int nb = 0; nb < 8; ++nb) {
    int col = nb * 16 + c;
    float tv = t_lds[col];
#pragma unroll
    for (int i = 0; i < 4; ++i) {
      out[(size_t)(rbase + kg * 4 + i) * 128 + col] = acc[nb][i] + tv;
    }
  }
}

extern "C" void kernel_launch(void* const* d_in, const int* in_sizes, int n_in,
                              void* d_out, int out_size, void* d_ws, size_t ws_size,
                              hipStream_t stream) {
  const float* x = (const float*)d_in[0];
  const float* w1 = (const float*)d_in[1];
  const float* w2 = (const float*)d_in[2];
  const float* bias = (const float*)d_in[3];
  float* out = (float*)d_out;
  int n = in_sizes[0] / 128;  // 200000
  int nb = n / 64;            // 3125

  char* ws = (char*)d_ws;
  float* t = (float*)ws;                     // 512 B
  ushort* w1p = (ushort*)(ws + 512);         // 34,816 B -> ends 35,328
  float* partial = (float*)(ws + 35328);     // 3125*128*4 = 1,600,000 B -> ends 1,635,328
  float* partial2 = (float*)(ws + 1635328);  // 65,536 B

  hipLaunchKernelGGL(colsum_pack_kernel, dim3(nb + PK_BLOCKS), dim3(256), 0, stream,
                     x, w1, w1p, (float4*)partial);
  hipLaunchKernelGGL(reduce_kernel, dim3(64), dim3(256), 0, stream, partial, partial2, nb);
  hipLaunchKernelGGL(transmit_kernel, dim3(1), dim3(1024), 0, stream,
                     partial2, w2, bias, t, n, 128);
  hipLaunchKernelGGL(gemm_lds_kernel, dim3(nb), dim3(256), 0, stream, x, w1p, t, out);
}